// Round 5
// baseline (371.160 us; speedup 1.0000x reference)
//
#include <hip/hip_runtime.h>
#include <hip/hip_bf16.h>

#define EPS 1e-6f
#define H 512
#define W 512
#define NB 8
#define NC 8
#define NS 7
#define LOG2E 1.4426950408889634f

typedef float v2f __attribute__((ext_vector_type(2)));
__device__ __forceinline__ v2f sp(float s) { return (v2f){s, s}; }

__device__ __forceinline__ int refl(int t, int n) {
    if (t < 0) t = -t;
    if (t >= n) t = 2 * n - 2 - t;
    return t;
}

// ---------------- Kernel A: gaussian-smoothed max only (no u_sigma store) ---------
#define GW 256
#define GR 32
#define NBLK ((W / GW) * (H / GR))   // 32 slots per image

__global__ __launch_bounds__(256) void gauss_max_kernel(
    const float* __restrict__ est, const float* __restrict__ gauss,
    float* __restrict__ blockmax)
{
    const int tx = threadIdx.x, ty = threadIdx.y;
    const int x0 = blockIdx.x * GW;
    const int R  = blockIdx.y * GR + ty * 8;
    const int b  = blockIdx.z;
    const float* e = est + (size_t)b * H * W;
    const int c0 = x0 + tx * 4;

    const float g0 = sqrtf(gauss[0]);
    const float g1 = sqrtf(gauss[6]);
    const float g2 = sqrtf(gauss[12]);

    float4 h0, h1, h2, h3, h4;
    float m = 0.f;

#pragma unroll
    for (int k = 0; k < 12; k++) {
        const float* row = e + refl(R - 2 + k, H) * W;
        float4 v = *(const float4*)&row[c0];
        float em2 = __shfl_up(v.z, 1);
        float em1 = __shfl_up(v.w, 1);
        float ep1 = __shfl_down(v.x, 1);
        float ep2 = __shfl_down(v.y, 1);
        if (tx == 0) {
            if (x0 == 0) { em2 = v.z; em1 = v.y; }
            else         { em2 = row[c0 - 2]; em1 = row[c0 - 1]; }
        }
        if (tx == 63) {
            if (x0 + GW == W) { ep1 = v.z; ep2 = v.y; }
            else              { ep1 = row[c0 + 4]; ep2 = row[c0 + 5]; }
        }
        float4 hc;
        hc.x = g0 * (em2 + v.z) + g1 * (em1 + v.y) + g2 * v.x;
        hc.y = g0 * (em1 + v.w) + g1 * (v.x + v.z) + g2 * v.y;
        hc.z = g0 * (v.x + ep1) + g1 * (v.y + v.w) + g2 * v.z;
        hc.w = g0 * (v.y + ep2) + g1 * (v.z + ep1) + g2 * v.w;
        h0 = h1; h1 = h2; h2 = h3; h3 = h4; h4 = hc;
        if (k >= 4) {
            float ux = g0 * (h0.x + h4.x) + g1 * (h1.x + h3.x) + g2 * h2.x;
            float uy = g0 * (h0.y + h4.y) + g1 * (h1.y + h3.y) + g2 * h2.y;
            float uz = g0 * (h0.z + h4.z) + g1 * (h1.z + h3.z) + g2 * h2.z;
            float uw = g0 * (h0.w + h4.w) + g1 * (h1.w + h3.w) + g2 * h2.w;
            m = fmaxf(m, fmaxf(fmaxf(ux, uy), fmaxf(uz, uw)));
        }
    }

#pragma unroll
    for (int off = 32; off > 0; off >>= 1)
        m = fmaxf(m, __shfl_xor(m, off, 64));
    __shared__ float wm[4];
    if (tx == 0) wm[ty] = m;
    __syncthreads();
    if (tx == 0 && ty == 0) {
        float mm = fmaxf(fmaxf(wm[0], wm[1]), fmaxf(wm[2], wm[3]));
        blockmax[b * NBLK + blockIdx.y * gridDim.x + blockIdx.x] = mm;
    }
}

// ---------------- Kernel B: full stage, 64x16 tile, channel-packed fp32 ----------
#define TX 64
#define TY 16
#define ZW 66              // z/us region width  (TX+2)
#define ZH 18              // z/us region height (TY+2)
#define ZP 68              // even stride (8B-aligned rows)
#define EW 70              // est region width  (TX+6), halo 3
#define EH 22              // est region height (TY+6)
#define EP 72              // even stride
#define HW_ 66             // h-pass region width (33 pairs)
#define HH 22              // h-pass region height

__global__ __launch_bounds__(256) void stage_kernel(
    const float* __restrict__ est, const float* __restrict__ noisy,
    const float* __restrict__ blockmax,
    const float* __restrict__ filt,  // [8][9] this stage
    const float* __restrict__ wv, const float* __restrict__ bv,
    const float* __restrict__ lamp, const float* __restrict__ gatep,
    const float* __restrict__ gauss,
    float* __restrict__ out)
{
    __shared__ float esh[EH][EP];
    __shared__ float ush[ZH][ZP];          // iw (pre-clamped/scaled, 0 outside image)
    __shared__ float zsh[ZH][ZP][NC];      // channel-minor; h-pass buffer overlays
    __shared__ float fshP[9][NC];          // tap-major, channel-minor (shared by z & syn)
    __shared__ float wshP[NC], bshP[NC];

    const int tx = threadIdx.x, ty = threadIdx.y;   // block (64,4)
    const int tid = ty * 64 + tx;
    const int x0 = blockIdx.x * TX, y0 = blockIdx.y * TY;
    const int b = blockIdx.z;
    const float* e  = est   + (size_t)b * H * W;
    const float* nz = noisy + (size_t)b * H * W;

    if (tid < 72) fshP[tid % 9][tid / 9] = filt[tid];
    else if (tid < 80) {
        int c = tid - 72;
        wshP[c] = wv[c] * (2.f * LOG2E);   // tanh in exp2 domain
        bshP[c] = bv[c] * (2.f * LOG2E);
    }

    const float g0 = sqrtf(gauss[0]);
    const float g1 = sqrtf(gauss[6]);
    const float g2 = sqrtf(gauss[12]);

    float m = blockmax[b * NBLK + (tid & 31)];
#pragma unroll
    for (int off = 16; off > 0; off >>= 1)
        m = fmaxf(m, __shfl_xor(m, off, 64));
    const float dinv = __builtin_amdgcn_rcpf(fmaxf(m, EPS));

    const float lam = lamp[0];
    const float g = __builtin_amdgcn_rcpf(1.f + __builtin_amdgcn_exp2f(-gatep[0] * LOG2E));

    // stage est tile + halo 3 (reflect)
    for (int i = tid; i < EH * EW; i += 256) {
        int ly = i / EW, lx = i % EW;
        esh[ly][lx] = e[refl(y0 + ly - 3, H) * W + refl(x0 + lx - 3, W)];
    }
    __syncthreads();

    // gaussian h-pass (pixel pairs) into overlay buffer
    float* hb = &zsh[0][0][0];             // HH x ZP region (consumed before z writes)
    for (int i = tid; i < HH * 33; i += 256) {
        int ly = i / 33, lx = 2 * (i % 33);
        v2f a = *(const v2f*)&esh[ly][lx];
        v2f bb = *(const v2f*)&esh[ly][lx + 2];
        v2f c = *(const v2f*)&esh[ly][lx + 4];
        v2f s04 = a + c;
        v2f s13 = (v2f){a.y, bb.x} + (v2f){bb.y, c.x};
        v2f u = sp(g0) * s04 + sp(g1) * s13 + sp(g2) * bb;
        *(v2f*)&hb[ly * ZP + lx] = u;
    }
    __syncthreads();

    // v-pass -> iw (pixel pairs), zero outside image
    for (int i = tid; i < ZH * 33; i += 256) {
        int ly = i / 33, lx = 2 * (i % 33);
        v2f h0v = *(const v2f*)&hb[(ly + 0) * ZP + lx];
        v2f h1v = *(const v2f*)&hb[(ly + 1) * ZP + lx];
        v2f h2v = *(const v2f*)&hb[(ly + 2) * ZP + lx];
        v2f h3v = *(const v2f*)&hb[(ly + 3) * ZP + lx];
        v2f h4v = *(const v2f*)&hb[(ly + 4) * ZP + lx];
        v2f u = sp(g0) * (h0v + h4v) + sp(g1) * (h1v + h3v) + sp(g2) * h2v;
        u = u * sp(dinv);
        u.x = fmaxf(u.x, EPS); u.y = fmaxf(u.y, EPS);
        int gy = y0 + ly - 1, gx = x0 + lx - 1;
        bool vy = (gy >= 0 && gy < H);
        float o0 = (vy && gx >= 0     && gx < W)     ? u.x : 0.f;
        float o1 = (vy && gx + 1 >= 0 && gx + 1 < W) ? u.y : 0.f;
        *(v2f*)&ush[ly][lx] = (v2f){o0, o1};
    }
    __syncthreads();   // hb consumed; zsh may now be overwritten

    // z over the 66x18 region, channels packed as 4 x v2f
    for (int i = tid; i < ZH * ZW; i += 256) {
        int ly = i / ZW, lx = i % ZW;
        float iw = ush[ly][lx];
        float ew[9];
#pragma unroll
        for (int dy = 0; dy < 3; dy++)
#pragma unroll
            for (int dx = 0; dx < 3; dx++)
                ew[dy * 3 + dx] = esh[ly + 1 + dy][lx + 1 + dx];
        v2f r[4] = {sp(0.f), sp(0.f), sp(0.f), sp(0.f)};
#pragma unroll
        for (int k = 0; k < 9; k++) {
            const v2f* fp = (const v2f*)&fshP[k][0];
            v2f es = sp(ew[k]);
            r[0] += es * fp[0];
            r[1] += es * fp[1];
            r[2] += es * fp[2];
            r[3] += es * fp[3];
        }
        float* zp = &zsh[ly][lx][0];
#pragma unroll
        for (int j = 0; j < 4; j++) {
            const v2f* wp = (const v2f*)&wshP[0];
            const v2f* bp = (const v2f*)&bshP[0];
            v2f wr = wp[j] * r[j] + bp[j];
            float a0 = __builtin_amdgcn_exp2f(wr.x);
            float a1 = __builtin_amdgcn_exp2f(wr.y);
            float t0 = 1.f - 2.f * __builtin_amdgcn_rcpf(a0 + 1.f);
            float t1 = 1.f - 2.f * __builtin_amdgcn_rcpf(a1 + 1.f);
            *(v2f*)(zp + 2 * j) = sp(iw) * (v2f){t0, t1};
        }
    }
    __syncthreads();

    // synthesis: each thread -> 2 rows x 2 cols, channel-packed accumulation
    const int p = tid & 31;          // col pair: cols 2p, 2p+1
    const int r0 = (tid >> 5) * 2;   // rows r0, r0+1
    const int xc = 2 * p;

    v2f fr[9][4];
#pragma unroll
    for (int k = 0; k < 9; k++)
#pragma unroll
        for (int j = 0; j < 4; j++)
            fr[k][j] = *(const v2f*)&fshP[k][2 * j];

    v2f acc[2][2][4];
#pragma unroll
    for (int a = 0; a < 2; a++)
#pragma unroll
        for (int c = 0; c < 2; c++)
#pragma unroll
            for (int j = 0; j < 4; j++)
                acc[a][c][j] = sp(0.f);

#pragma unroll
    for (int dr = 0; dr < 4; dr++) {
#pragma unroll
        for (int dc = 0; dc < 4; dc++) {
            const float* zp = &zsh[r0 + dr][xc + dc][0];
            v2f zv0 = *(const v2f*)(zp + 0);
            v2f zv1 = *(const v2f*)(zp + 2);
            v2f zv2 = *(const v2f*)(zp + 4);
            v2f zv3 = *(const v2f*)(zp + 6);
#pragma unroll
            for (int orow = 0; orow < 2; orow++) {
                int ky = dr - orow;
                if (ky < 0 || ky > 2) continue;
#pragma unroll
                for (int ocol = 0; ocol < 2; ocol++) {
                    int kx = dc - ocol;
                    if (kx < 0 || kx > 2) continue;
                    int tap = ky * 3 + kx;
                    acc[orow][ocol][0] += zv0 * fr[tap][0];
                    acc[orow][ocol][1] += zv1 * fr[tap][1];
                    acc[orow][ocol][2] += zv2 * fr[tap][2];
                    acc[orow][ocol][3] += zv3 * fr[tap][3];
                }
            }
        }
    }

#pragma unroll
    for (int orow = 0; orow < 2; orow++) {
        const int r = r0 + orow;
        const int y = y0 + r;
        v2f n2 = *(const v2f*)&nz[(size_t)y * W + x0 + xc];
        v2f res;
#pragma unroll
        for (int ocol = 0; ocol < 2; ocol++) {
            v2f s = (acc[orow][ocol][0] + acc[orow][ocol][1])
                  + (acc[orow][ocol][2] + acc[orow][ocol][3]);
            float diff = s.x + s.y;
            float eo = esh[r + 3][xc + 3 + ocol];
            float n0 = (ocol == 0) ? n2.x : n2.y;
            float iwc = ush[r + 1][xc + 1 + ocol];
            float fg = (eo - n0) * __builtin_amdgcn_rcpf(eo * eo + EPS);
            float est2 = eo - diff - lam * iwc * fg;
            float en = est2 + g * (n0 - est2);
            en = fminf(fmaxf(en, EPS), 1.f);
            if (ocol == 0) res.x = en; else res.y = en;
        }
        *(v2f*)&out[(size_t)b * H * W + (size_t)y * W + x0 + xc] = res;
    }
}

extern "C" void kernel_launch(void* const* d_in, const int* in_sizes, int n_in,
                              void* d_out, int out_size, void* d_ws, size_t ws_size,
                              hipStream_t stream)
{
    const float* noisy   = (const float*)d_in[0];
    const float* filters = (const float*)d_in[1];  // [7][8][1][3][3]
    const float* wv      = (const float*)d_in[2];  // [7][8]
    const float* bv      = (const float*)d_in[3];  // [7][8]
    const float* lam     = (const float*)d_in[4];  // [7]
    const float* gate    = (const float*)d_in[5];  // [7]
    const float* gauss   = (const float*)d_in[6];  // [25]
    float* out = (float*)d_out;

    char* ws = (char*)d_ws;
    float* ws0      = (float*)ws;                    // 8 MB ping buffer
    float* blockmax = (float*)(ws + (8u << 20));     // 32*8 floats, rewritten each stage

    const float* cur = noisy;
    for (int s = 0; s < NS; s++) {
        float* nxt = (s % 2 == 0) ? out : ws0;  // odd stage count -> final lands in out
        gauss_max_kernel<<<dim3(W / GW, H / GR, NB), dim3(64, 4), 0, stream>>>(
            cur, gauss, blockmax);
        stage_kernel<<<dim3(W / TX, H / TY, NB), dim3(64, 4), 0, stream>>>(
            cur, noisy, blockmax,
            filters + s * NC * 9, wv + s * NC, bv + s * NC, lam + s, gate + s, gauss, nxt);
        cur = nxt;
    }
}